// Round 1
// baseline (1333.986 us; speedup 1.0000x reference)
//
#include <hip/hip_runtime.h>

#define DD 128
#define TILE_E 64
#define LDW 136   // padded LDS row stride (bf16 elems): 272 B = 68 dwords -> bank shift 4/row

typedef __attribute__((ext_vector_type(8))) short short8;
typedef __attribute__((ext_vector_type(4))) float f32x4;

__device__ __forceinline__ unsigned short f2bf(float f) {
  unsigned int u = __float_as_uint(f);
  u += 0x7FFF + ((u >> 16) & 1);   // RNE
  return (unsigned short)(u >> 16);
}

// K1: node_messages[dest[e]] += relu(edge_feats[e])
__global__ __launch_bounds__(256) void scatter_relu_kernel(
    const float* __restrict__ ef, const int* __restrict__ eidx,
    float* __restrict__ nm, int E) {
  int idx = blockIdx.x * 256 + threadIdx.x;     // over E * D/4 float4s
  if (idx >= E * (DD / 4)) return;
  int e  = idx >> 5;                            // D/4 = 32 float4 per edge
  int k4 = idx & 31;
  float4 v = ((const float4*)ef)[idx];
  v.x = fmaxf(v.x, 0.f); v.y = fmaxf(v.y, 0.f);
  v.z = fmaxf(v.z, 0.f); v.w = fmaxf(v.w, 0.f);
  int d = eidx[E + e];                          // edge_index row 1 = dest
  float* p = nm + (size_t)d * DD + (k4 << 2);
  atomicAdd(p + 0, v.x);
  atomicAdd(p + 1, v.y);
  atomicAdd(p + 2, v.z);
  atomicAdd(p + 3, v.w);
}

// K2: out[e,:] = (nm[src[e],:] - relu(ef[rev[e],:])) @ W^T + b   via bf16 MFMA
__global__ __launch_bounds__(256) void fused_gather_gemm_kernel(
    const float* __restrict__ ef, const float* __restrict__ nm,
    const float* __restrict__ W, const float* __restrict__ bias,
    const int* __restrict__ eidx, const int* __restrict__ rev,
    float* __restrict__ out, int E) {
  __shared__ unsigned short Wl[DD * LDW];       // Wl[n][k] = bf16(W[n][k])  (34816 B)
  __shared__ unsigned short Al[TILE_E * LDW];   // Al[e][k] = bf16(em)       (17408 B)
  const int tid = threadIdx.x;

  // stage W -> LDS bf16 (each block; W is L2-resident so cheap)
  #pragma unroll
  for (int i = 0; i < 16; ++i) {
    int idx = tid + i * 256;                    // 4096 float4s = 128x128
    int n   = idx >> 5;
    int k4  = idx & 31;
    float4 w = ((const float4*)W)[idx];
    unsigned int lo = f2bf(w.x) | ((unsigned int)f2bf(w.y) << 16);
    unsigned int hi = f2bf(w.z) | ((unsigned int)f2bf(w.w) << 16);
    *(uint2*)&Wl[n * LDW + (k4 << 2)] = make_uint2(lo, hi);
  }

  // stage em tile: 64 edges x 128 k, 4 threads per edge
  const int e0 = blockIdx.x * TILE_E;
  {
    int el = tid >> 2;                          // 0..63
    int kb = (tid & 3) << 3;                    // float4 base index (8 per thread)
    int e  = e0 + el;
    int s = 0, rv = 0;
    if (e < E) { s = eidx[e]; rv = rev[e]; }    // row 0 = src
    const float4* nmp = (const float4*)(nm + (size_t)s  * DD);
    const float4* efp = (const float4*)(ef + (size_t)rv * DD);
    #pragma unroll
    for (int i = 0; i < 8; ++i) {
      int k4 = kb + i;
      float4 a = nmp[k4];
      float4 m = efp[k4];
      float x0 = a.x - fmaxf(m.x, 0.f);
      float x1 = a.y - fmaxf(m.y, 0.f);
      float x2 = a.z - fmaxf(m.z, 0.f);
      float x3 = a.w - fmaxf(m.w, 0.f);
      unsigned int lo = f2bf(x0) | ((unsigned int)f2bf(x1) << 16);
      unsigned int hi = f2bf(x2) | ((unsigned int)f2bf(x3) << 16);
      *(uint2*)&Al[el * LDW + (k4 << 2)] = make_uint2(lo, hi);
    }
  }
  __syncthreads();

  const int lane = tid & 63;
  const int wave = tid >> 6;                    // 4 waves, 16 edges each
  const int col  = lane & 15;
  const int quad = lane >> 4;
  const int erow = wave * 16;

  f32x4 acc[8];
  #pragma unroll
  for (int i = 0; i < 8; ++i) acc[i] = (f32x4){0.f, 0.f, 0.f, 0.f};

  #pragma unroll
  for (int kt = 0; kt < 4; ++kt) {
    const int k0 = kt * 32 + quad * 8;          // A[m=col][k0..k0+7]
    short8 a = *(const short8*)&Al[(erow + col) * LDW + k0];
    #pragma unroll
    for (int nt = 0; nt < 8; ++nt) {
      // B[k][n]=W[n][k]: lane holds n=col, k=k0..k0+7
      short8 b = *(const short8*)&Wl[(nt * 16 + col) * LDW + k0];
      acc[nt] = __builtin_amdgcn_mfma_f32_16x16x32_bf16(a, b, acc[nt], 0, 0, 0);
    }
  }

  // epilogue: D[row=quad*4+r][col], +bias
  #pragma unroll
  for (int nt = 0; nt < 8; ++nt) {
    float bj = bias[nt * 16 + col];
    #pragma unroll
    for (int r = 0; r < 4; ++r) {
      int e = e0 + erow + quad * 4 + r;
      if (e < E) out[(size_t)e * DD + nt * 16 + col] = acc[nt][r] + bj;
    }
  }
}

extern "C" void kernel_launch(void* const* d_in, const int* in_sizes, int n_in,
                              void* d_out, int out_size, void* d_ws, size_t ws_size,
                              hipStream_t stream) {
  const float* ef   = (const float*)d_in[0];
  // d_in[1] node_feats: only its length (V) is used by the reference
  const float* W    = (const float*)d_in[2];
  const float* bias = (const float*)d_in[3];
  const int*   eidx = (const int*)d_in[4];     // [2,E]: row0=src, row1=dest
  const int*   rev  = (const int*)d_in[5];     // [E]
  float*       out  = (float*)d_out;

  const int V = in_sizes[1];
  const int E = in_sizes[5];

  float* nm = (float*)d_ws;                     // [V,128] fp32 accumulator
  hipMemsetAsync(nm, 0, (size_t)V * DD * sizeof(float), stream);

  int total = E * (DD / 4);
  scatter_relu_kernel<<<(total + 255) / 256, 256, 0, stream>>>(ef, eidx, nm, E);

  int nblocks = (E + TILE_E - 1) / TILE_E;
  fused_gather_gemm_kernel<<<nblocks, 256, 0, stream>>>(ef, nm, W, bias, eidx, rev, out, E);
}

// Round 2
// 780.936 us; speedup vs baseline: 1.7082x; 1.7082x over previous
//
#include <hip/hip_runtime.h>

#define DD 128
#define TILE_E 64
#define LDW 136   // padded LDS row stride (bf16 elems): 272 B/row -> bank shift 4/row

typedef __attribute__((ext_vector_type(8))) short short8;
typedef __attribute__((ext_vector_type(4))) float f32x4;

__device__ __forceinline__ unsigned short f2bf(float f) {
  unsigned int u = __float_as_uint(f);
  u += 0x7FFF + ((u >> 16) & 1);   // RNE
  return (unsigned short)(u >> 16);
}

// ---- Phase A: build dest-sorted edge list (replaces 64M fp32 atomics) ----

__global__ __launch_bounds__(256) void hist_kernel(
    const int* __restrict__ eidx, int* __restrict__ cnt, int E) {
  int e = blockIdx.x * 256 + threadIdx.x;
  if (e < E) atomicAdd(&cnt[eidx[E + e]], 1);
}

// single-block exclusive scan over V counts -> off, and copy -> cur
__global__ __launch_bounds__(1024) void scan_kernel(
    const int* __restrict__ cnt, int* __restrict__ off, int* __restrict__ cur, int V) {
  __shared__ int s[1024];
  const int t = threadIdx.x;
  const int chunk = (V + 1023) / 1024;
  const int lo = t * chunk, hi = min(lo + chunk, V);
  int tot = 0;
  for (int v = lo; v < hi; ++v) tot += cnt[v];
  s[t] = tot;
  __syncthreads();
  // Hillis-Steele inclusive scan of thread totals
  for (int d = 1; d < 1024; d <<= 1) {
    int x = (t >= d) ? s[t - d] : 0;
    __syncthreads();
    s[t] += x;
    __syncthreads();
  }
  int run = (t > 0) ? s[t - 1] : 0;
  for (int v = lo; v < hi; ++v) {
    off[v] = run; cur[v] = run;
    run += cnt[v];
  }
}

__global__ __launch_bounds__(256) void fill_kernel(
    const int* __restrict__ eidx, int* __restrict__ cur,
    int* __restrict__ elist, int E) {
  int e = blockIdx.x * 256 + threadIdx.x;
  if (e < E) {
    int p = atomicAdd(&cur[eidx[E + e]], 1);
    elist[p] = e;
  }
}

// ---- Phase B: nm[v,:] = sum_{e: dest[e]=v} relu(ef[e,:])  (one wave per node) ----
__global__ __launch_bounds__(256) void gather_sum_kernel(
    const float* __restrict__ ef, const int* __restrict__ off,
    const int* __restrict__ cnt, const int* __restrict__ elist,
    float* __restrict__ nm, int V) {
  const int lane = threadIdx.x & 63;
  const int v = blockIdx.x * 4 + (threadIdx.x >> 6);
  if (v >= V) return;
  const int base = off[v];
  const int deg  = cnt[v];
  float2 acc = make_float2(0.f, 0.f);
  for (int j = 0; j < deg; ++j) {
    int e = elist[base + j];
    float2 m = ((const float2*)(ef + (size_t)e * DD))[lane];
    acc.x += fmaxf(m.x, 0.f);
    acc.y += fmaxf(m.y, 0.f);
  }
  ((float2*)(nm + (size_t)v * DD))[lane] = acc;
}

// ---- W -> bf16 precompute (once per launch) ----
__global__ __launch_bounds__(256) void wconv_kernel(
    const float* __restrict__ W, unsigned short* __restrict__ Wbf) {
  int idx = blockIdx.x * 256 + threadIdx.x;   // over 4096 float4s
  if (idx >= DD * DD / 4) return;
  float4 w = ((const float4*)W)[idx];
  unsigned int lo = f2bf(w.x) | ((unsigned int)f2bf(w.y) << 16);
  unsigned int hi = f2bf(w.z) | ((unsigned int)f2bf(w.w) << 16);
  *(uint2*)&Wbf[idx * 4] = make_uint2(lo, hi);
}

// ---- Phase C: out[e,:] = (nm[src[e],:] - relu(ef[rev[e],:])) @ W^T + b ----
__global__ __launch_bounds__(256) void fused_gather_gemm_kernel(
    const float* __restrict__ ef, const float* __restrict__ nm,
    const unsigned short* __restrict__ Wbf, const float* __restrict__ bias,
    const int* __restrict__ eidx, const int* __restrict__ rev,
    float* __restrict__ out, int E) {
  __shared__ __align__(16) unsigned short Wl[DD * LDW];   // 34816 B
  __shared__ __align__(16) unsigned short Al[TILE_E * LDW]; // 17408 B
  const int tid = threadIdx.x;

  // stage bf16 W -> LDS (32KB, no conversion)
  #pragma unroll
  for (int i = 0; i < 8; ++i) {
    int idx = tid + i * 256;                  // 2048 uint4s = 128 rows x 16
    int n   = idx >> 4;
    int k8  = idx & 15;
    uint4 w = ((const uint4*)Wbf)[idx];
    *(uint4*)&Wl[n * LDW + (k8 << 3)] = w;
  }

  // stage em tile: 64 edges x 128 k, 4 threads per edge
  const int e0 = blockIdx.x * TILE_E;
  {
    int el = tid >> 2;                        // 0..63
    int kb = (tid & 3) << 3;                  // float4 base (8 per thread)
    int e  = e0 + el;
    int s = 0, rv = 0;
    if (e < E) { s = eidx[e]; rv = rev[e]; }  // row 0 = src
    const float4* nmp = (const float4*)(nm + (size_t)s  * DD);
    const float4* efp = (const float4*)(ef + (size_t)rv * DD);
    #pragma unroll
    for (int i = 0; i < 8; ++i) {
      int k4 = kb + i;
      float4 a = nmp[k4];
      float4 m = efp[k4];
      float x0 = a.x - fmaxf(m.x, 0.f);
      float x1 = a.y - fmaxf(m.y, 0.f);
      float x2 = a.z - fmaxf(m.z, 0.f);
      float x3 = a.w - fmaxf(m.w, 0.f);
      unsigned int lo = f2bf(x0) | ((unsigned int)f2bf(x1) << 16);
      unsigned int hi = f2bf(x2) | ((unsigned int)f2bf(x3) << 16);
      *(uint2*)&Al[el * LDW + (k4 << 2)] = make_uint2(lo, hi);
    }
  }
  __syncthreads();

  const int lane = tid & 63;
  const int wave = tid >> 6;                  // 4 waves, 16 edges each
  const int col  = lane & 15;
  const int quad = lane >> 4;
  const int erow = wave * 16;

  f32x4 acc[8];
  #pragma unroll
  for (int i = 0; i < 8; ++i) acc[i] = (f32x4){0.f, 0.f, 0.f, 0.f};

  #pragma unroll
  for (int kt = 0; kt < 4; ++kt) {
    const int k0 = kt * 32 + quad * 8;        // A[m=col][k0..k0+7]
    short8 a = *(const short8*)&Al[(erow + col) * LDW + k0];
    #pragma unroll
    for (int nt = 0; nt < 8; ++nt) {
      short8 b = *(const short8*)&Wl[(nt * 16 + col) * LDW + k0];
      acc[nt] = __builtin_amdgcn_mfma_f32_16x16x32_bf16(a, b, acc[nt], 0, 0, 0);
    }
  }

  // epilogue: D[row=quad*4+r][col], +bias
  #pragma unroll
  for (int nt = 0; nt < 8; ++nt) {
    float bj = bias[nt * 16 + col];
    #pragma unroll
    for (int r = 0; r < 4; ++r) {
      int e = e0 + erow + quad * 4 + r;
      if (e < E) out[(size_t)e * DD + nt * 16 + col] = acc[nt][r] + bj;
    }
  }
}

extern "C" void kernel_launch(void* const* d_in, const int* in_sizes, int n_in,
                              void* d_out, int out_size, void* d_ws, size_t ws_size,
                              hipStream_t stream) {
  const float* ef   = (const float*)d_in[0];
  const float* W    = (const float*)d_in[2];
  const float* bias = (const float*)d_in[3];
  const int*   eidx = (const int*)d_in[4];   // [2,E]: row0=src, row1=dest (int32 per harness)
  const int*   rev  = (const int*)d_in[5];   // [E]
  float*       out  = (float*)d_out;

  const int V = in_sizes[1];
  const int E = in_sizes[5];

  // workspace layout (256B-aligned slices)
  char* ws = (char*)d_ws;
  size_t o = 0;
  float* nm = (float*)(ws + o);            o += (size_t)V * DD * sizeof(float);
  o = (o + 255) & ~(size_t)255;
  int* cnt  = (int*)(ws + o);              o += (size_t)V * sizeof(int);
  o = (o + 255) & ~(size_t)255;
  int* off  = (int*)(ws + o);              o += (size_t)V * sizeof(int);
  o = (o + 255) & ~(size_t)255;
  int* cur  = (int*)(ws + o);              o += (size_t)V * sizeof(int);
  o = (o + 255) & ~(size_t)255;
  int* elist = (int*)(ws + o);             o += (size_t)E * sizeof(int);
  o = (o + 255) & ~(size_t)255;
  unsigned short* Wbf = (unsigned short*)(ws + o);

  hipMemsetAsync(cnt, 0, (size_t)V * sizeof(int), stream);

  int eb = (E + 255) / 256;
  hist_kernel<<<eb, 256, 0, stream>>>(eidx, cnt, E);
  scan_kernel<<<1, 1024, 0, stream>>>(cnt, off, cur, V);
  fill_kernel<<<eb, 256, 0, stream>>>(eidx, cur, elist, E);
  gather_sum_kernel<<<(V + 3) / 4, 256, 0, stream>>>(ef, off, cnt, elist, nm, V);
  wconv_kernel<<<(DD * DD / 4 + 255) / 256, 256, 0, stream>>>(W, Wbf);

  int nblocks = (E + TILE_E - 1) / TILE_E;
  fused_gather_gemm_kernel<<<nblocks, 256, 0, stream>>>(ef, nm, Wbf, bias, eidx, rev, out, E);
}